// Round 12
// baseline (1656.950 us; speedup 1.0000x reference)
//
#include <hip/hip_runtime.h>
#include <hip/hip_bf16.h>
#include <cstdint>

// Problem constants (from reference)
#define TT     2048   // tokens
#define KSEL   6      // experts per token
#define DMODEL 2048   // model dim
#define DINTER 1408   // moe intermediate dim
#define NE     16     // routed experts
#define PMAX   (TT * KSEL)

typedef short bf16x8 __attribute__((ext_vector_type(8)));
typedef float f32x4 __attribute__((ext_vector_type(4)));
typedef unsigned short u16;
typedef u16 u16x8 __attribute__((ext_vector_type(8)));

__device__ __forceinline__ u16 f2bf(float f) {
  union { float f; unsigned u; } v; v.f = f;
  return (u16)((v.u + 0x7FFFu + ((v.u >> 16) & 1u)) >> 16);  // RNE
}

// fp32->bf16 via HIP cast (compiler emits packed cvt; RNE)
__device__ __forceinline__ u16 f2bfh(float f) {
  __hip_bfloat16 h = __float2bfloat16(f);
  u16 r; __builtin_memcpy(&r, &h, 2); return r;
}

__device__ __forceinline__ void gl2lds16(const void* g, void* l) {
  __builtin_amdgcn_global_load_lds((const __attribute__((address_space(1))) void*)g,
                                   (__attribute__((address_space(3))) void*)l,
                                   16, 0, 0);
}

#define BAR_RAW() asm volatile("s_barrier" ::: "memory")
// full drain BEFORE issuing next-tile B loads: at this point B(kb) is already
// consumed (register data dependence) and B(kb+1) not yet issued, so this only
// drains the A gl2lds + commits ds_writes — order-robust vs compiler scheduling
// (R9's counted vmcnt(16) assumed an issue order LLVM doesn't guarantee -> NaN).
#define DRAIN() asm volatile("s_waitcnt vmcnt(0) lgkmcnt(0)" ::: "memory")

// gate_w[t,e] = sum_k weights[t,k]*(indices[t,k]==e); count routed (t,e) pairs
__global__ void k_gate(const float* __restrict__ w, const int* __restrict__ idx,
                       float* __restrict__ gate_w, int* __restrict__ counts) {
  int g = blockIdx.x * 256 + threadIdx.x;  // T*E threads
  int t = g >> 4, e = g & 15;
  const int* ip = idx + t * KSEL;
  const float* wp = w + t * KSEL;
  float s = 0.f;
#pragma unroll
  for (int k = 0; k < KSEL; ++k) s += (ip[k] == e) ? wp[k] : 0.f;
  gate_w[g] = s;
  if (s != 0.f) atomicAdd(counts + e, 1);
}

__global__ void k_scan(const int* __restrict__ counts, int* __restrict__ offs) {
  if (threadIdx.x == 0 && blockIdx.x == 0) {
    int r = 0;
#pragma unroll
    for (int e = 0; e < NE; ++e) { offs[e] = r; r += counts[e]; }
    offs[NE] = r;
  }
}

__global__ void k_fill(const float* __restrict__ gate_w, const int* __restrict__ offs,
                       int* __restrict__ cursor, int* __restrict__ slot_tok,
                       float* __restrict__ slot_gate) {
  int g = blockIdx.x * 256 + threadIdx.x;
  int t = g >> 4, e = g & 15;
  float s = gate_w[g];
  if (s != 0.f) {
    int p = atomicAdd(cursor + e, 1);
    int sl = offs[e] + p;
    slot_tok[sl] = t;
    slot_gate[sl] = s;
  }
}

// fp32 -> bf16 cast for x only (16 MB)
__global__ void k_castx(const float* __restrict__ x, u16* __restrict__ xb) {
  int i = blockIdx.x * 256 + threadIdx.x;  // 8 elems per thread
  const float4* p = (const float4*)x + (size_t)i * 2;
  float4 v0 = p[0], v1 = p[1];
  u16x8 o;
  o[0] = f2bf(v0.x); o[1] = f2bf(v0.y); o[2] = f2bf(v0.z); o[3] = f2bf(v0.w);
  o[4] = f2bf(v1.x); o[5] = f2bf(v1.y); o[6] = f2bf(v1.z); o[7] = f2bf(v1.w);
  *(u16x8*)(xb + (size_t)i * 8) = o;
}

// ---------------------------------------------------------------------------
// GEMM1 with FUSED weight cast: B (Wg,Wu) staged fp32 global->reg->bf16->
// swizzled ds_write; next-tile B loads issued AFTER a full drain so they
// stay in flight across the barrier + MFMA phase (T14, order-robust form).
// A (xb) staged via global_load_lds (R6 path). Compute/epilogue = R6.
// LDS rows 64 bf16 = 8 16B-units; XOR swizzle unit' = unit ^ (row&7) on
// write AND read sides (rule #21).
// ---------------------------------------------------------------------------
__global__ __launch_bounds__(256, 2) void k_gemm1(
    const u16* __restrict__ xb, const float* __restrict__ Wg, const float* __restrict__ Wu,
    const int* __restrict__ slot_tok, const float* __restrict__ slot_gate,
    const int* __restrict__ offs, const int* __restrict__ counts,
    u16* __restrict__ act) {
  // linear e-major order: 16 mt-blocks sharing an (it,e) fp32 panel run in a
  // tight window -> L2/L3 absorb the re-reads; weights fetched ~once from HBM.
  int b = blockIdx.x;
  int mt = b & 15, rest = b >> 4;
  int it = rest % 11, e = rest / 11;

  int mcount = counts[e];
  if (mt * 128 >= mcount) return;
  int mrem = mcount - mt * 128; if (mrem > 128) mrem = 128;
  int slotBase = offs[e] + mt * 128;
  int iBase = it * 128;

  __shared__ u16 sA[128 * 64];
  __shared__ u16 sG[128 * 64];
  __shared__ u16 sU[128 * 64];
  __shared__ int tokLds[128];
  __shared__ float gateLds[128];

  int tid = threadIdx.x;
  if (tid < 128) {
    int rl = tid < mrem ? tid : 0;
    tokLds[tid] = slot_tok[slotBase + rl];
    gateLds[tid] = (tid < mrem) ? slot_gate[slotBase + rl] : 0.f;
  }
  __syncthreads();

  int wv = tid >> 6, lane = tid & 63;
  // A staging (R6): 16 chunks of 1KB; linear LDS dest, source unit pre-swizzled
  const u16* aSrc[4]; u16* aDst[4];
  int r8 = lane >> 3;
  int colOff = ((lane & 7) ^ r8) * 8;
#pragma unroll
  for (int i2 = 0; i2 < 4; ++i2) {
    int chunk = wv * 4 + i2;
    int row = chunk * 8 + r8;
    aSrc[i2] = xb + (size_t)tokLds[row] * DMODEL + colOff;
    aDst[i2] = sA + chunk * 512;
  }

  // B fp32 staging: 128 rows x 64 cols fp32 per tensor per K-step.
  // thread -> row = tid>>1, col half = (tid&1)*32; 8 float4 loads per tensor.
  int srow = tid >> 1, sc0 = (tid & 1) * 32;
  const float* gS = Wg + ((size_t)e * DINTER + iBase + srow) * DMODEL + sc0;
  const float* uS = Wu + ((size_t)e * DINTER + iBase + srow) * DMODEL + sc0;
  int wrBase = srow * 64;
  int u4 = (tid & 1) * 4;

  f32x4 vg[8], vu[8];
  auto LOADB = [&](int kk) {
#pragma unroll
    for (int j = 0; j < 8; ++j) {
      vg[j] = *(const f32x4*)(gS + kk * 64 + j * 4);
      vu[j] = *(const f32x4*)(uS + kk * 64 + j * 4);
    }
  };

  f32x4 accg[4][4] = {};
  f32x4 accu[4][4] = {};
  int fr = lane & 15, fq = lane >> 4;
  int wr = (wv >> 1) * 64, wc = (wv & 1) * 64;

  LOADB(0);   // prologue: tile-0 B loads in flight

#pragma unroll 1
  for (int kb = 0; kb < DMODEL / 64; ++kb) {
    BAR_RAW();                         // all waves done reading prev LDS tile
#pragma unroll
    for (int i2 = 0; i2 < 4; ++i2) gl2lds16(aSrc[i2] + kb * 64, aDst[i2]);
    // convert B(kb) (register dep auto-waits its loads) + swizzled ds_write
#pragma unroll
    for (int w = 0; w < 4; ++w) {
      union { u16 h[8]; bf16x8 v; } og, ou;
#pragma unroll
      for (int q = 0; q < 8; ++q) {
        og.h[q] = f2bfh(vg[w * 2 + (q >> 2)][q & 3]);
        ou.h[q] = f2bfh(vu[w * 2 + (q >> 2)][q & 3]);
      }
      int du = (((u4 + w) ^ (srow & 7)) << 3);
      *(bf16x8*)&sG[wrBase + du] = og.v;
      *(bf16x8*)&sU[wrBase + du] = ou.v;
    }
    DRAIN();                           // A landed + ds_writes committed
    LOADB((kb + 1) & 31);              // next-tile B: in flight across barrier
    BAR_RAW();
#pragma unroll
    for (int kf = 0; kf < 2; ++kf) {
      bf16x8 af[4], bg[4], bu[4];
#pragma unroll
      for (int mf = 0; mf < 4; ++mf) {
        int row = wr + mf * 16 + fr;
        int cu = ((kf * 4 + fq) ^ (row & 7)) * 8;
        af[mf] = *(const bf16x8*)&sA[row * 64 + cu];
      }
#pragma unroll
      for (int nf = 0; nf < 4; ++nf) {
        int row = wc + nf * 16 + fr;
        int cu = ((kf * 4 + fq) ^ (row & 7)) * 8;
        bg[nf] = *(const bf16x8*)&sG[row * 64 + cu];
        bu[nf] = *(const bf16x8*)&sU[row * 64 + cu];
      }
#pragma unroll
      for (int mf = 0; mf < 4; ++mf)
#pragma unroll
        for (int nf = 0; nf < 4; ++nf) {
          accg[mf][nf] = __builtin_amdgcn_mfma_f32_16x16x32_bf16(af[mf], bg[nf], accg[mf][nf], 0, 0, 0);
          accu[mf][nf] = __builtin_amdgcn_mfma_f32_16x16x32_bf16(af[mf], bu[nf], accu[mf][nf], 0, 0, 0);
        }
    }
  }
  // epilogue: act = silu(g)*u*gate -> bf16  (D layout: col=lane&15, row=(lane>>4)*4+r)
#pragma unroll
  for (int mf = 0; mf < 4; ++mf)
#pragma unroll
    for (int nf = 0; nf < 4; ++nf)
#pragma unroll
      for (int r = 0; r < 4; ++r) {
        int row = wr + mf * 16 + fq * 4 + r;
        if (row < mrem) {
          float g = accg[mf][nf][r], u = accu[mf][nf][r];
          float a = g / (1.f + __expf(-g)) * u * gateLds[row];
          act[(size_t)(slotBase + row) * DINTER + iBase + wc + nf * 16 + fr] = f2bf(a);
        }
      }
}

// GEMM2 with fused Wd cast: same order-robust T14 B path; A = act via
// global_load_lds (R6). y scatter via atomicAdd (<=6 adds/elem).
__global__ __launch_bounds__(256, 3) void k_gemm2(
    const u16* __restrict__ act, const float* __restrict__ Wd,
    const int* __restrict__ slot_tok, const int* __restrict__ offs,
    const int* __restrict__ counts, float* __restrict__ y) {
  int b = blockIdx.x;                  // linear: mt fastest, then dt, then e
  int mt = b & 15, rest = b >> 4;
  int dt = rest & 15, e = rest >> 4;

  int mcount = counts[e];
  if (mt * 128 >= mcount) return;
  int mrem = mcount - mt * 128; if (mrem > 128) mrem = 128;
  int slotBase = offs[e] + mt * 128;
  int dBase = dt * 128;

  __shared__ u16 sA[128 * 64];
  __shared__ u16 sB[128 * 64];
  __shared__ int tokLds[128];

  int tid = threadIdx.x;
  if (tid < 128) tokLds[tid] = slot_tok[slotBase + (tid < mrem ? tid : 0)];
  __syncthreads();

  int wv = tid >> 6, lane = tid & 63;
  const u16* aSrc[4]; u16* aDst[4];
  int r8 = lane >> 3;
  int colOff = ((lane & 7) ^ r8) * 8;
#pragma unroll
  for (int i2 = 0; i2 < 4; ++i2) {
    int chunk = wv * 4 + i2;
    int row = chunk * 8 + r8;
    aSrc[i2] = act + (size_t)(slotBase + row) * DINTER + colOff;  // act padded rows
    aDst[i2] = sA + chunk * 512;
  }

  int srow = tid >> 1, sc0 = (tid & 1) * 32;
  const float* bS = Wd + ((size_t)e * DMODEL + dBase + srow) * DINTER + sc0;
  int wrBase = srow * 64;
  int u4 = (tid & 1) * 4;

  f32x4 vb[8];
  auto LOADB = [&](int kk) {
#pragma unroll
    for (int j = 0; j < 8; ++j) vb[j] = *(const f32x4*)(bS + kk * 64 + j * 4);
  };

  f32x4 acc[4][4] = {};
  int fr = lane & 15, fq = lane >> 4;
  int wr = (wv >> 1) * 64, wc = (wv & 1) * 64;

  const int NT = DINTER / 64;  // 22
  LOADB(0);

#pragma unroll 1
  for (int kb = 0; kb < NT; ++kb) {
    BAR_RAW();
#pragma unroll
    for (int i2 = 0; i2 < 4; ++i2) gl2lds16(aSrc[i2] + kb * 64, aDst[i2]);
#pragma unroll
    for (int w = 0; w < 4; ++w) {
      union { u16 h[8]; bf16x8 v; } ob;
#pragma unroll
      for (int q = 0; q < 8; ++q) ob.h[q] = f2bfh(vb[w * 2 + (q >> 2)][q & 3]);
      int du = (((u4 + w) ^ (srow & 7)) << 3);
      *(bf16x8*)&sB[wrBase + du] = ob.v;
    }
    DRAIN();
    LOADB((kb + 1 == NT) ? 0 : kb + 1);
    BAR_RAW();
#pragma unroll
    for (int kf = 0; kf < 2; ++kf) {
      bf16x8 af[4], bb[4];
#pragma unroll
      for (int mf = 0; mf < 4; ++mf) {
        int row = wr + mf * 16 + fr;
        int cu = ((kf * 4 + fq) ^ (row & 7)) * 8;
        af[mf] = *(const bf16x8*)&sA[row * 64 + cu];
      }
#pragma unroll
      for (int nf = 0; nf < 4; ++nf) {
        int row = wc + nf * 16 + fr;
        int cu = ((kf * 4 + fq) ^ (row & 7)) * 8;
        bb[nf] = *(const bf16x8*)&sB[row * 64 + cu];
      }
#pragma unroll
      for (int mf = 0; mf < 4; ++mf)
#pragma unroll
        for (int nf = 0; nf < 4; ++nf)
          acc[mf][nf] = __builtin_amdgcn_mfma_f32_16x16x32_bf16(af[mf], bb[nf], acc[mf][nf], 0, 0, 0);
    }
  }
#pragma unroll
  for (int mf = 0; mf < 4; ++mf)
#pragma unroll
    for (int nf = 0; nf < 4; ++nf)
#pragma unroll
      for (int r = 0; r < 4; ++r) {
        int row = wr + mf * 16 + fq * 4 + r;
        if (row < mrem) {
          int t = tokLds[row];
          atomicAdd(y + (size_t)t * DMODEL + dBase + wc + nf * 16 + fr, acc[mf][nf][r]);
        }
      }
}

extern "C" void kernel_launch(void* const* d_in, const int* in_sizes, int n_in,
                              void* d_out, int out_size, void* d_ws, size_t ws_size,
                              hipStream_t stream) {
  const float* x       = (const float*)d_in[0];
  const float* weights = (const float*)d_in[1];
  const int*   indices = (const int*)d_in[2];
  const float* Wg      = (const float*)d_in[3];
  const float* Wu      = (const float*)d_in[4];
  const float* Wd      = (const float*)d_in[5];
  float* y = (float*)d_out;

  char* ws = (char*)d_ws;
  size_t o = 0;
  float* gate_w = (float*)(ws + o); o += (size_t)TT * NE * 4;
  size_t ctrlOff = o;
  int* counts = (int*)(ws + o);
  int* offs   = (int*)(ws + o + 64);
  int* cursor = (int*)(ws + o + 192);
  o += 256;
  int*   slot_tok  = (int*)(ws + o);   o += (size_t)PMAX * 4;
  float* slot_gate = (float*)(ws + o); o += (size_t)PMAX * 4;
  u16* xb  = (u16*)(ws + o); o += (size_t)TT * DMODEL * 2;
  u16* act = (u16*)(ws + o); o += (size_t)(PMAX + 256) * DINTER * 2; // pad rows
  (void)ws_size; (void)in_sizes; (void)n_in;

  hipMemsetAsync(d_out, 0, (size_t)out_size * 4, stream);
  hipMemsetAsync(ws + ctrlOff, 0, 256, stream);

  k_gate<<<TT * NE / 256, 256, 0, stream>>>(weights, indices, gate_w, counts);
  k_scan<<<1, 64, 0, stream>>>(counts, offs);
  k_fill<<<TT * NE / 256, 256, 0, stream>>>(gate_w, offs, cursor, slot_tok, slot_gate);
  k_castx<<<(TT * DMODEL / 8) / 256, 256, 0, stream>>>(x, xb);
  k_gemm1<<<2816, 256, 0, stream>>>(xb, Wg, Wu, slot_tok, slot_gate, offs, counts, act);
  k_gemm2<<<4096, 256, 0, stream>>>(act, Wd, slot_tok, offs, counts, y);
}

// Round 13
// 724.428 us; speedup vs baseline: 2.2873x; 2.2873x over previous
//
#include <hip/hip_runtime.h>
#include <hip/hip_bf16.h>
#include <cstdint>

// Problem constants (from reference)
#define TT     2048   // tokens
#define KSEL   6      // experts per token
#define DMODEL 2048   // model dim
#define DINTER 1408   // moe intermediate dim
#define NE     16     // routed experts
#define PMAX   (TT * KSEL)

typedef short bf16x8 __attribute__((ext_vector_type(8)));
typedef float f32x4 __attribute__((ext_vector_type(4)));
typedef unsigned short u16;
typedef u16 u16x8 __attribute__((ext_vector_type(8)));

__device__ __forceinline__ u16 f2bf(float f) {
  union { float f; unsigned u; } v; v.f = f;
  return (u16)((v.u + 0x7FFFu + ((v.u >> 16) & 1u)) >> 16);  // RNE
}

__device__ __forceinline__ void gl2lds16(const void* g, void* l) {
  __builtin_amdgcn_global_load_lds((const __attribute__((address_space(1))) void*)g,
                                   (__attribute__((address_space(3))) void*)l,
                                   16, 0, 0);
}

// gate_w[t,e] = sum_k weights[t,k]*(indices[t,k]==e); count routed (t,e) pairs
__global__ void k_gate(const float* __restrict__ w, const int* __restrict__ idx,
                       float* __restrict__ gate_w, int* __restrict__ counts) {
  int g = blockIdx.x * 256 + threadIdx.x;  // T*E threads
  int t = g >> 4, e = g & 15;
  const int* ip = idx + t * KSEL;
  const float* wp = w + t * KSEL;
  float s = 0.f;
#pragma unroll
  for (int k = 0; k < KSEL; ++k) s += (ip[k] == e) ? wp[k] : 0.f;
  gate_w[g] = s;
  if (s != 0.f) atomicAdd(counts + e, 1);
}

__global__ void k_scan(const int* __restrict__ counts, int* __restrict__ offs) {
  if (threadIdx.x == 0 && blockIdx.x == 0) {
    int r = 0;
#pragma unroll
    for (int e = 0; e < NE; ++e) { offs[e] = r; r += counts[e]; }
    offs[NE] = r;
  }
}

__global__ void k_fill(const float* __restrict__ gate_w, const int* __restrict__ offs,
                       int* __restrict__ cursor, int* __restrict__ slot_tok,
                       float* __restrict__ slot_gate) {
  int g = blockIdx.x * 256 + threadIdx.x;
  int t = g >> 4, e = g & 15;
  float s = gate_w[g];
  if (s != 0.f) {
    int p = atomicAdd(cursor + e, 1);
    int sl = offs[e] + p;
    slot_tok[sl] = t;
    slot_gate[sl] = s;
  }
}

// fp32->bf16 cast for x + Wg + Wu (Wd is cast inside the gemm1 launch)
#define XV8   (TT * DMODEL / 8)                      // 524288
#define WV8   (NE * DINTER * DMODEL / 8)             // 5767168
__global__ void k_cast3(const float* __restrict__ x,  u16* __restrict__ xb,
                        const float* __restrict__ wg, u16* __restrict__ wgb,
                        const float* __restrict__ wu, u16* __restrict__ wub) {
  const int total = XV8 + 2 * WV8;
  int stride = gridDim.x * 256;
  for (int i = blockIdx.x * 256 + threadIdx.x; i < total; i += stride) {
    const float* src; u16* dst; int j;
    if (i < XV8)            { src = x;  dst = xb;  j = i; }
    else if (i < XV8 + WV8) { src = wg; dst = wgb; j = i - XV8; }
    else                    { src = wu; dst = wub; j = i - XV8 - WV8; }
    const float4* p = (const float4*)src + (size_t)j * 2;
    float4 v0 = p[0], v1 = p[1];
    u16x8 o;
    o[0] = f2bf(v0.x); o[1] = f2bf(v0.y); o[2] = f2bf(v0.z); o[3] = f2bf(v0.w);
    o[4] = f2bf(v1.x); o[5] = f2bf(v1.y); o[6] = f2bf(v1.z); o[7] = f2bf(v1.w);
    *(u16x8*)(dst + (size_t)j * 8) = o;
  }
}

// ---------------------------------------------------------------------------
// GEMM1 (R6-exact core) + embedded castWd role blocks.
// Grid = 3520 = 440 octets of 8; octets with (q%5==4) are castWd (88*8=704
// blocks), the rest decode to the 2816 gemm work-ids. Octet interleave keeps
// b%8 == g%8, preserving the XCD-chunk property (same (it,e) panel -> same
// XCD L2). Cast traffic (345 MB) hides under gemm1's 9%-HBM compute window.
// ---------------------------------------------------------------------------
__global__ __launch_bounds__(256, 2) void k_gemm1(
    const u16* __restrict__ xb, const u16* __restrict__ wgb, const u16* __restrict__ wub,
    const float* __restrict__ Wd, u16* __restrict__ wdb,
    const int* __restrict__ slot_tok, const float* __restrict__ slot_gate,
    const int* __restrict__ offs, const int* __restrict__ counts,
    u16* __restrict__ act) {
  int bq = blockIdx.x >> 3, br = blockIdx.x & 7;
  if (bq % 5 == 4) {
    // ---- castWd role: 704 blocks x 8192 items x 8 elems ----
    int c = (bq / 5) * 8 + br;
    int base = c * 8192;
#pragma unroll 4
    for (int it = 0; it < 32; ++it) {
      int j = base + it * 256 + threadIdx.x;
      const float4* p = (const float4*)Wd + (size_t)j * 2;
      float4 v0 = p[0], v1 = p[1];
      u16x8 o;
      o[0] = f2bf(v0.x); o[1] = f2bf(v0.y); o[2] = f2bf(v0.z); o[3] = f2bf(v0.w);
      o[4] = f2bf(v1.x); o[5] = f2bf(v1.y); o[6] = f2bf(v1.z); o[7] = f2bf(v1.w);
      *(u16x8*)(wdb + (size_t)j * 8) = o;
    }
    return;
  }
  int g = ((bq / 5) * 4 + (bq % 5)) * 8 + br;       // [0, 2816)
  // XCD-chunked swizzle (R6): w = (g&7)*352 + g>>3
  int w = (g & 7) * 352 + (g >> 3);
  int mt = w & 15, rest = w >> 4;
  int it = rest % 11, e = rest / 11;

  int mcount = counts[e];
  if (mt * 128 >= mcount) return;
  int mrem = mcount - mt * 128; if (mrem > 128) mrem = 128;
  int slotBase = offs[e] + mt * 128;
  int iBase = it * 128;

  __shared__ u16 sA[128 * 64];
  __shared__ u16 sG[128 * 64];
  __shared__ u16 sU[128 * 64];
  __shared__ int tokLds[128];
  __shared__ float gateLds[128];

  int tid = threadIdx.x;
  if (tid < 128) {
    int rl = tid < mrem ? tid : 0;        // pad rows clamp to row 0 (valid addr)
    tokLds[tid] = slot_tok[slotBase + rl];
    gateLds[tid] = (tid < mrem) ? slot_gate[slotBase + rl] : 0.f;
  }
  __syncthreads();

  int wv = tid >> 6, lane = tid & 63;
  // staging: 16 chunks of 1KB (8 rows x 128B); linear LDS dest, swizzled source
  const u16 *aSrc[4], *gSrc[4], *uSrc[4];
  u16 *aDst[4], *gDst[4], *uDst[4];
  const u16* gBase = wgb + ((size_t)e * DINTER + iBase) * DMODEL;
  const u16* uBase = wub + ((size_t)e * DINTER + iBase) * DMODEL;
  int r8 = lane >> 3;
  int colOff = ((lane & 7) ^ r8) * 8;   // swizzled 16B-unit within the row
#pragma unroll
  for (int i2 = 0; i2 < 4; ++i2) {
    int chunk = wv * 4 + i2;
    int row = chunk * 8 + r8;
    aSrc[i2] = xb + (size_t)tokLds[row] * DMODEL + colOff;
    gSrc[i2] = gBase + (size_t)row * DMODEL + colOff;
    uSrc[i2] = uBase + (size_t)row * DMODEL + colOff;
    aDst[i2] = sA + chunk * 512;
    gDst[i2] = sG + chunk * 512;
    uDst[i2] = sU + chunk * 512;
  }

  f32x4 accg[4][4] = {};
  f32x4 accu[4][4] = {};
  int fr = lane & 15, fq = lane >> 4;
  int wr = (wv >> 1) * 64, wc = (wv & 1) * 64;

  for (int kb = 0; kb < DMODEL / 64; ++kb) {
    int kOff = kb * 64;
    __syncthreads();
#pragma unroll
    for (int i2 = 0; i2 < 4; ++i2) {
      gl2lds16(aSrc[i2] + kOff, aDst[i2]);
      gl2lds16(gSrc[i2] + kOff, gDst[i2]);
      gl2lds16(uSrc[i2] + kOff, uDst[i2]);
    }
    __syncthreads();
#pragma unroll
    for (int kf = 0; kf < 2; ++kf) {
      bf16x8 af[4], bg[4], bu[4];
#pragma unroll
      for (int mf = 0; mf < 4; ++mf) {
        int row = wr + mf * 16 + fr;
        int cu = ((kf * 4 + fq) ^ (row & 7)) * 8;
        af[mf] = *(const bf16x8*)&sA[row * 64 + cu];
      }
#pragma unroll
      for (int nf = 0; nf < 4; ++nf) {
        int row = wc + nf * 16 + fr;
        int cu = ((kf * 4 + fq) ^ (row & 7)) * 8;
        bg[nf] = *(const bf16x8*)&sG[row * 64 + cu];
        bu[nf] = *(const bf16x8*)&sU[row * 64 + cu];
      }
#pragma unroll
      for (int mf = 0; mf < 4; ++mf)
#pragma unroll
        for (int nf = 0; nf < 4; ++nf) {
          accg[mf][nf] = __builtin_amdgcn_mfma_f32_16x16x32_bf16(af[mf], bg[nf], accg[mf][nf], 0, 0, 0);
          accu[mf][nf] = __builtin_amdgcn_mfma_f32_16x16x32_bf16(af[mf], bu[nf], accu[mf][nf], 0, 0, 0);
        }
    }
  }
  // epilogue: act = silu(g)*u*gate -> bf16  (D layout: col=lane&15, row=(lane>>4)*4+r)
#pragma unroll
  for (int mf = 0; mf < 4; ++mf)
#pragma unroll
    for (int nf = 0; nf < 4; ++nf)
#pragma unroll
      for (int r = 0; r < 4; ++r) {
        int row = wr + mf * 16 + fq * 4 + r;
        if (row < mrem) {
          float gv = accg[mf][nf][r], uv = accu[mf][nf][r];
          float a = gv / (1.f + __expf(-gv)) * uv * gateLds[row];
          act[(size_t)(slotBase + row) * DINTER + iBase + wc + nf * 16 + fr] = f2bf(a);
        }
      }
}

// ---------------------------------------------------------------------------
// GEMM2 dual-dt: one A-tile (act 128xK) feeds TWO 128-col Wd panels, dual
// accumulators — same per-K-step shape as gemm1's proven profile (32 MFMA/
// wave/step, 48 KB staged). 22 K-steps. Atomic scatter into y (<=6 adds/elem).
// ---------------------------------------------------------------------------
__global__ __launch_bounds__(256, 3) void k_gemm2(
    const u16* __restrict__ act, const u16* __restrict__ wdb,
    const int* __restrict__ slot_tok, const int* __restrict__ offs,
    const int* __restrict__ counts, float* __restrict__ y) {
  // grid flat = 16(mt) x 8(dtp) x 16(e) = 2048 = 8*256; XCD-chunked
  int b = blockIdx.x;
  int w = (b & 7) * 256 + (b >> 3);
  int mt = w & 15, rest = w >> 4;
  int dtp = rest & 7, e = rest >> 3;

  int mcount = counts[e];
  if (mt * 128 >= mcount) return;
  int mrem = mcount - mt * 128; if (mrem > 128) mrem = 128;
  int slotBase = offs[e] + mt * 128;
  int dBase0 = dtp * 256, dBase1 = dtp * 256 + 128;

  __shared__ u16 sA[128 * 64];
  __shared__ u16 sB0[128 * 64];
  __shared__ u16 sB1[128 * 64];
  __shared__ int tokLds[128];

  int tid = threadIdx.x;
  if (tid < 128) tokLds[tid] = slot_tok[slotBase + (tid < mrem ? tid : 0)];
  __syncthreads();

  int wv = tid >> 6, lane = tid & 63;
  const u16 *aSrc[4], *b0Src[4], *b1Src[4];
  u16 *aDst[4], *b0Dst[4], *b1Dst[4];
  const u16* b0Base = wdb + ((size_t)e * DMODEL + dBase0) * DINTER;
  const u16* b1Base = wdb + ((size_t)e * DMODEL + dBase1) * DINTER;
  int r8 = lane >> 3;
  int colOff = ((lane & 7) ^ r8) * 8;   // swizzled 16B-unit
#pragma unroll
  for (int i2 = 0; i2 < 4; ++i2) {
    int chunk = wv * 4 + i2;
    int row = chunk * 8 + r8;
    aSrc[i2]  = act + (size_t)(slotBase + row) * DINTER + colOff;  // act padded rows
    b0Src[i2] = b0Base + (size_t)row * DINTER + colOff;
    b1Src[i2] = b1Base + (size_t)row * DINTER + colOff;
    aDst[i2]  = sA  + chunk * 512;
    b0Dst[i2] = sB0 + chunk * 512;
    b1Dst[i2] = sB1 + chunk * 512;
  }

  f32x4 acc0[4][4] = {};
  f32x4 acc1[4][4] = {};
  int fr = lane & 15, fq = lane >> 4;
  int wr = (wv >> 1) * 64, wc = (wv & 1) * 64;

  for (int kb = 0; kb < DINTER / 64; ++kb) {
    int kOff = kb * 64;
    __syncthreads();
#pragma unroll
    for (int i2 = 0; i2 < 4; ++i2) {
      gl2lds16(aSrc[i2] + kOff, aDst[i2]);
      gl2lds16(b0Src[i2] + kOff, b0Dst[i2]);
      gl2lds16(b1Src[i2] + kOff, b1Dst[i2]);
    }
    __syncthreads();
#pragma unroll
    for (int kf = 0; kf < 2; ++kf) {
      bf16x8 af[4], bb0[4], bb1[4];
#pragma unroll
      for (int mf = 0; mf < 4; ++mf) {
        int row = wr + mf * 16 + fr;
        int cu = ((kf * 4 + fq) ^ (row & 7)) * 8;
        af[mf] = *(const bf16x8*)&sA[row * 64 + cu];
      }
#pragma unroll
      for (int nf = 0; nf < 4; ++nf) {
        int row = wc + nf * 16 + fr;
        int cu = ((kf * 4 + fq) ^ (row & 7)) * 8;
        bb0[nf] = *(const bf16x8*)&sB0[row * 64 + cu];
        bb1[nf] = *(const bf16x8*)&sB1[row * 64 + cu];
      }
#pragma unroll
      for (int mf = 0; mf < 4; ++mf)
#pragma unroll
        for (int nf = 0; nf < 4; ++nf) {
          acc0[mf][nf] = __builtin_amdgcn_mfma_f32_16x16x32_bf16(af[mf], bb0[nf], acc0[mf][nf], 0, 0, 0);
          acc1[mf][nf] = __builtin_amdgcn_mfma_f32_16x16x32_bf16(af[mf], bb1[nf], acc1[mf][nf], 0, 0, 0);
        }
    }
  }
#pragma unroll
  for (int mf = 0; mf < 4; ++mf)
#pragma unroll
    for (int nf = 0; nf < 4; ++nf)
#pragma unroll
      for (int r = 0; r < 4; ++r) {
        int row = wr + mf * 16 + fq * 4 + r;
        if (row < mrem) {
          int t = tokLds[row];
          atomicAdd(y + (size_t)t * DMODEL + dBase0 + wc + nf * 16 + fr, acc0[mf][nf][r]);
          atomicAdd(y + (size_t)t * DMODEL + dBase1 + wc + nf * 16 + fr, acc1[mf][nf][r]);
        }
      }
}

extern "C" void kernel_launch(void* const* d_in, const int* in_sizes, int n_in,
                              void* d_out, int out_size, void* d_ws, size_t ws_size,
                              hipStream_t stream) {
  const float* x       = (const float*)d_in[0];
  const float* weights = (const float*)d_in[1];
  const int*   indices = (const int*)d_in[2];
  const float* Wg      = (const float*)d_in[3];
  const float* Wu      = (const float*)d_in[4];
  const float* Wd      = (const float*)d_in[5];
  float* y = (float*)d_out;

  const size_t WELEM = (size_t)NE * DINTER * DMODEL;  // 46.1M elems per weight tensor

  char* ws = (char*)d_ws;
  size_t o = 0;
  float* gate_w = (float*)(ws + o); o += (size_t)TT * NE * 4;
  size_t ctrlOff = o;
  int* counts = (int*)(ws + o);
  int* offs   = (int*)(ws + o + 64);
  int* cursor = (int*)(ws + o + 192);
  o += 256;
  int*   slot_tok  = (int*)(ws + o);   o += (size_t)PMAX * 4;
  float* slot_gate = (float*)(ws + o); o += (size_t)PMAX * 4;
  u16* xb  = (u16*)(ws + o); o += (size_t)TT * DMODEL * 2;
  u16* act = (u16*)(ws + o); o += (size_t)(PMAX + 256) * DINTER * 2; // pad rows
  u16* wgb = (u16*)(ws + o); o += WELEM * 2;
  u16* wub = (u16*)(ws + o); o += WELEM * 2;
  u16* wdb = (u16*)(ws + o); o += WELEM * 2;   // total ~306 MB
  (void)ws_size; (void)in_sizes; (void)n_in;

  hipMemsetAsync(d_out, 0, (size_t)out_size * 4, stream);
  hipMemsetAsync(ws + ctrlOff, 0, 256, stream);

  k_gate<<<TT * NE / 256, 256, 0, stream>>>(weights, indices, gate_w, counts);
  k_scan<<<1, 64, 0, stream>>>(counts, offs);
  k_fill<<<TT * NE / 256, 256, 0, stream>>>(gate_w, offs, cursor, slot_tok, slot_gate);
  k_cast3<<<2048, 256, 0, stream>>>(x, xb, Wg, wgb, Wu, wub);
  k_gemm1<<<3520, 256, 0, stream>>>(xb, wgb, wub, Wd, wdb, slot_tok, slot_gate,
                                    offs, counts, act);
  k_gemm2<<<2048, 256, 0, stream>>>(act, wdb, slot_tok, offs, counts, y);
}